// Round 1
// baseline (593.349 us; speedup 1.0000x reference)
//
#include <hip/hip_runtime.h>

// InterestEvolve: attention-modulated GRU scan.
// B=2048, T=200, D=128, U=128. Output h_final (B,U) fp32.
//
// Design: 128 workgroups x 256 threads (4 waves). Each WG owns 16 batch rows.
// Wave w owns gate columns [32w, 32w+32) of u, r, hh (2 MFMA 16x16 col-tiles).
// Weights as MFMA B-fragments in registers (bf16, ln2-prescaled).
// h kept fp32 in registers (per-wave own cols); bf16 copy of full h tile in
// LDS for the cross-wave A-operand broadcast. r*h round-trips LDS as bf16.
// x A-fragments loaded directly from global (layout matches A-frag addressing),
// prefetched one timestep ahead.

#define T_LEN 200
#define D_DIM 128
#define U_DIM 128
#define BM    16
#define LSTR  136   // LDS row stride in bf16 elems (128 + 8 pad -> 2-way-max conflicts)

typedef __attribute__((ext_vector_type(8))) short bf16x8;
typedef __attribute__((ext_vector_type(4))) float f32x4;

static __device__ __forceinline__ unsigned short f2bf(float f) {
    unsigned int u = __builtin_bit_cast(unsigned int, f);
    u += 0x7fffu + ((u >> 16) & 1u);       // round-to-nearest-even
    return (unsigned short)(u >> 16);
}
static __device__ __forceinline__ float bf2f(unsigned short b) {
    unsigned int u = ((unsigned int)b) << 16;
    return __builtin_bit_cast(float, u);
}
static __device__ __forceinline__ bf16x8 pack8(float4 lo, float4 hi) {
    bf16x8 v;
    v[0] = (short)f2bf(lo.x); v[1] = (short)f2bf(lo.y);
    v[2] = (short)f2bf(lo.z); v[3] = (short)f2bf(lo.w);
    v[4] = (short)f2bf(hi.x); v[5] = (short)f2bf(hi.y);
    v[6] = (short)f2bf(hi.z); v[7] = (short)f2bf(hi.w);
    return v;
}

static __device__ __forceinline__ float fast_exp2(float x) {
#if __has_builtin(__builtin_amdgcn_exp2f)
    return __builtin_amdgcn_exp2f(x);
#else
    return exp2f(x);
#endif
}
static __device__ __forceinline__ float fast_rcp(float x) {
#if __has_builtin(__builtin_amdgcn_rcpf)
    return __builtin_amdgcn_rcpf(x);
#else
    return 1.0f / x;
#endif
}

__global__ __launch_bounds__(256, 1)
void gru_scan_kernel(const float* __restrict__ X,    // (B,T,D)
                     const float* __restrict__ Att,  // (B,T,1)
                     const float* __restrict__ Wu, const float* __restrict__ bu,
                     const float* __restrict__ Wr, const float* __restrict__ br,
                     const float* __restrict__ Wh, const float* __restrict__ bh,
                     float* __restrict__ out)        // (B,U)
{
    __shared__ unsigned short h_bf[BM * LSTR];   // h_t, bf16, [row=batch][col=gate]
    __shared__ unsigned short rh_bf[BM * LSTR];  // r*h, bf16, same layout
    __shared__ float a_sm[BM];                   // attention a_t per batch row

    const int tid  = threadIdx.x;
    const int wave = tid >> 6;
    const int lane = tid & 63;
    const int q    = lane >> 4;   // quad 0..3
    const int ln   = lane & 15;
    const int b0   = blockIdx.x * BM;
    const int colb = wave * 32;   // this wave's gate-col base (2 tiles of 16)

    const float INVLN2 = 1.4426950408889634f;

    // ---- Build weight B-fragments in registers.
    // B-frag layout (16x16x32): lane holds col n = lane&15 (+tile base),
    // k = 32*kt + 8*quad + j, j=0..7.  GEMM1 k: [h(0:128) | x(128:256)] rows of
    // Wu/Wr (matches hx=concat([h,x])).  GEMM2 k: [x(0:128) | r*h(128:256)]
    // rows of Wh (matches concat([x, r*h])).
    // ln2 pre-fold: Wu,Wr scaled by -1/ln2 (sigmoid via exp2 of -z/ln2);
    // Wh scaled by 2/ln2 (tanh(z) = 1 - 2/(1+exp2(2z/ln2))).
    bf16x8 wu[2][8], wr[2][8], wh[2][8];
    float nbu[2], nbr[2], bh2[2];
    #pragma unroll
    for (int nt = 0; nt < 2; ++nt) {
        const int c = colb + nt * 16 + ln;
        nbu[nt] = -bu[c] * INVLN2;
        nbr[nt] = -br[c] * INVLN2;
        bh2[nt] = 2.0f * bh[c] * INVLN2;
        #pragma unroll
        for (int kt = 0; kt < 8; ++kt) {
            const int k0 = 32 * kt + 8 * q;
            bf16x8 vu, vr, vh;
            #pragma unroll
            for (int j = 0; j < 8; ++j) {
                vu[j] = (short)f2bf(Wu[(k0 + j) * U_DIM + c] * -INVLN2);
                vr[j] = (short)f2bf(Wr[(k0 + j) * U_DIM + c] * -INVLN2);
                vh[j] = (short)f2bf(Wh[(k0 + j) * U_DIM + c] * (2.0f * INVLN2));
            }
            wu[nt][kt] = vu; wr[nt][kt] = vr; wh[nt][kt] = vh;
        }
    }

    // ---- init ----
    float hreg[2][4];   // fp32 h for own cols: [tile][reg], row = 4q+reg, col = colb+16nt+ln
    #pragma unroll
    for (int nt = 0; nt < 2; ++nt)
        #pragma unroll
        for (int r = 0; r < 4; ++r) hreg[nt][r] = 0.0f;

    for (int i = tid; i < BM * LSTR; i += 256) h_bf[i] = 0;
    if (tid < BM) a_sm[tid] = Att[(size_t)(b0 + tid) * T_LEN];

    // x A-fragments: lane holds row m = ln (batch b0+ln), k(=d) = 32*i + 8q + j.
    const float* xrow = X + (size_t)(b0 + ln) * T_LEN * D_DIM;
    bf16x8 xfrag[4];
    #pragma unroll
    for (int i = 0; i < 4; ++i) {
        float4 lo = *(const float4*)(xrow + 32 * i + 8 * q);
        float4 hi = *(const float4*)(xrow + 32 * i + 8 * q + 4);
        xfrag[i] = pack8(lo, hi);
    }
    __syncthreads();

    for (int t = 0; t < T_LEN; ++t) {
        // ---------- phase A: prefetch x(t+1)/a(t+1), GEMM1 + GEMM2 x-part ----------
        const int tn = (t + 1 < T_LEN) ? (t + 1) : (T_LEN - 1);
        float4 px[8];
        #pragma unroll
        for (int i = 0; i < 4; ++i) {
            px[2*i]   = *(const float4*)(xrow + (size_t)tn * D_DIM + 32 * i + 8 * q);
            px[2*i+1] = *(const float4*)(xrow + (size_t)tn * D_DIM + 32 * i + 8 * q + 4);
        }
        float a_next = 0.0f;
        if (tid < BM) a_next = Att[(size_t)(b0 + tid) * T_LEN + tn];

        bf16x8 hfrag[4];
        #pragma unroll
        for (int kt = 0; kt < 4; ++kt)
            hfrag[kt] = *(const bf16x8*)&h_bf[ln * LSTR + 32 * kt + 8 * q];

        f32x4 accu[2], accr[2], acch[2];
        #pragma unroll
        for (int nt = 0; nt < 2; ++nt) {
            accu[nt] = (f32x4)0.0f; accr[nt] = (f32x4)0.0f; acch[nt] = (f32x4)0.0f;
        }
        #pragma unroll
        for (int kt = 0; kt < 4; ++kt) {
            #pragma unroll
            for (int nt = 0; nt < 2; ++nt) {
                accu[nt] = __builtin_amdgcn_mfma_f32_16x16x32_bf16(hfrag[kt], wu[nt][kt], accu[nt], 0, 0, 0);
                accr[nt] = __builtin_amdgcn_mfma_f32_16x16x32_bf16(hfrag[kt], wr[nt][kt], accr[nt], 0, 0, 0);
                acch[nt] = __builtin_amdgcn_mfma_f32_16x16x32_bf16(xfrag[kt], wh[nt][kt], acch[nt], 0, 0, 0);
            }
        }
        #pragma unroll
        for (int kt = 4; kt < 8; ++kt) {
            #pragma unroll
            for (int nt = 0; nt < 2; ++nt) {
                accu[nt] = __builtin_amdgcn_mfma_f32_16x16x32_bf16(xfrag[kt-4], wu[nt][kt], accu[nt], 0, 0, 0);
                accr[nt] = __builtin_amdgcn_mfma_f32_16x16x32_bf16(xfrag[kt-4], wr[nt][kt], accr[nt], 0, 0, 0);
            }
        }

        // ---------- phase B: gates u (stays in regs), r*h -> LDS bf16 ----------
        const f32x4 av = *(const f32x4*)&a_sm[4 * q];   // a[4q+r], broadcast in quad
        float uq[2][4];
        #pragma unroll
        for (int nt = 0; nt < 2; ++nt) {
            const int col = colb + nt * 16 + ln;
            #pragma unroll
            for (int r = 0; r < 4; ++r) {
                float zu = accu[nt][r] + nbu[nt];                       // = -z_u/ln2
                float u  = fast_rcp(1.0f + fast_exp2(zu));              // sigmoid
                uq[nt][r] = u * av[r];                                  // attention-modulated
                float zr = accr[nt][r] + nbr[nt];
                float rv = fast_rcp(1.0f + fast_exp2(zr));
                float hv = bf2f(h_bf[(4 * q + r) * LSTR + col]);        // h_t (bf16 ok: feeds bf16 A anyway)
                rh_bf[(4 * q + r) * LSTR + col] = f2bf(rv * hv);
            }
        }
        __syncthreads();   // rh handoff

        // ---------- phase C: GEMM2 rh-part ----------
        bf16x8 rfrag[4];
        #pragma unroll
        for (int kt = 0; kt < 4; ++kt)
            rfrag[kt] = *(const bf16x8*)&rh_bf[ln * LSTR + 32 * kt + 8 * q];
        #pragma unroll
        for (int kt = 0; kt < 4; ++kt)
            #pragma unroll
            for (int nt = 0; nt < 2; ++nt)
                acch[nt] = __builtin_amdgcn_mfma_f32_16x16x32_bf16(rfrag[kt], wh[nt][kt + 4], acch[nt], 0, 0, 0);

        // ---------- phase D: tanh, h update (fp32 in regs), publish bf16 h ----------
        #pragma unroll
        for (int nt = 0; nt < 2; ++nt) {
            const int col = colb + nt * 16 + ln;
            #pragma unroll
            for (int r = 0; r < 4; ++r) {
                float z  = acch[nt][r] + bh2[nt];                       // = 2*z_h/ln2
                float hh = 1.0f - 2.0f * fast_rcp(1.0f + fast_exp2(z)); // tanh
                float ho = hreg[nt][r];
                float hn = ho + uq[nt][r] * (hh - ho);                  // u*hh + (1-u)*h
                hreg[nt][r] = hn;
                h_bf[(4 * q + r) * LSTR + col] = f2bf(hn);
            }
        }
        // finish x prefetch (convert off the critical GEMM path)
        #pragma unroll
        for (int i = 0; i < 4; ++i) xfrag[i] = pack8(px[2*i], px[2*i+1]);
        if (tid < BM) a_sm[tid] = a_next;
        __syncthreads();   // h/a handoff to next step
    }

    // ---- store h_final ----
    #pragma unroll
    for (int nt = 0; nt < 2; ++nt) {
        const int col = colb + nt * 16 + ln;
        #pragma unroll
        for (int r = 0; r < 4; ++r)
            out[(size_t)(b0 + 4 * q + r) * U_DIM + col] = hreg[nt][r];
    }
}

extern "C" void kernel_launch(void* const* d_in, const int* in_sizes, int n_in,
                              void* d_out, int out_size, void* d_ws, size_t ws_size,
                              hipStream_t stream) {
    const float* X   = (const float*)d_in[0];
    const float* Att = (const float*)d_in[1];
    const float* Wu  = (const float*)d_in[2];
    const float* bu  = (const float*)d_in[3];
    const float* Wr  = (const float*)d_in[4];
    const float* br  = (const float*)d_in[5];
    const float* Wh  = (const float*)d_in[6];
    const float* bh  = (const float*)d_in[7];
    float* out = (float*)d_out;

    gru_scan_kernel<<<dim3(2048 / BM), dim3(256), 0, stream>>>(
        X, Att, Wu, bu, Wr, br, Wh, bh, out);
}

// Round 2
// 572.121 us; speedup vs baseline: 1.0371x; 1.0371x over previous
//
#include <hip/hip_runtime.h>

// InterestEvolve: attention-modulated GRU scan. B=2048, T=200, D=128, U=128.
//
// R2: chunked LDS staging of x/attention (bf16, A-frag layout, 12 steps/chunk)
// removes per-step global loads (whose vmcnt(0) drain at every barrier was the
// R1 stall) and dedups the fp32->bf16 conversion across the 4 waves.
// r*h now uses the fp32 register copy of h. accu/accr split into 2 accumulators
// (chain depth 4). u-gate sigmoid moved after the rh barrier to overlap
// phase-C MFMA latency.

#define T_LEN 200
#define D_DIM 128
#define U_DIM 128
#define BM    16
#define LSTR  136   // LDS row stride in bf16 elems (128 + 8 pad)
#define CH    12    // staged timesteps per chunk; 17 chunks (last = 8)

typedef __attribute__((ext_vector_type(8))) short bf16x8;
typedef __attribute__((ext_vector_type(4))) float f32x4;

static __device__ __forceinline__ unsigned short f2bf(float f) {
    unsigned int u = __builtin_bit_cast(unsigned int, f);
    u += 0x7fffu + ((u >> 16) & 1u);       // round-to-nearest-even
    return (unsigned short)(u >> 16);
}
static __device__ __forceinline__ bf16x8 pack8(float4 lo, float4 hi) {
    bf16x8 v;
    v[0] = (short)f2bf(lo.x); v[1] = (short)f2bf(lo.y);
    v[2] = (short)f2bf(lo.z); v[3] = (short)f2bf(lo.w);
    v[4] = (short)f2bf(hi.x); v[5] = (short)f2bf(hi.y);
    v[6] = (short)f2bf(hi.z); v[7] = (short)f2bf(hi.w);
    return v;
}
static __device__ __forceinline__ float fast_exp2(float x) {
#if __has_builtin(__builtin_amdgcn_exp2f)
    return __builtin_amdgcn_exp2f(x);
#else
    return exp2f(x);
#endif
}
static __device__ __forceinline__ float fast_rcp(float x) {
#if __has_builtin(__builtin_amdgcn_rcpf)
    return __builtin_amdgcn_rcpf(x);
#else
    return 1.0f / x;
#endif
}

__global__ __launch_bounds__(256, 1)
void gru_scan_kernel(const float* __restrict__ X,    // (B,T,D)
                     const float* __restrict__ Att,  // (B,T,1)
                     const float* __restrict__ Wu, const float* __restrict__ bu,
                     const float* __restrict__ Wr, const float* __restrict__ br,
                     const float* __restrict__ Wh, const float* __restrict__ bh,
                     float* __restrict__ out)        // (B,U)
{
    __shared__ unsigned short x_sm[CH * BM * LSTR];  // 52224 B, bf16 x-chunk
    __shared__ unsigned short h_bf[BM * LSTR];       // 4352 B
    __shared__ unsigned short rh_bf[BM * LSTR];      // 4352 B
    __shared__ float a_sm[CH * BM];                  // 768 B   (total 61696 B)

    const int tid  = threadIdx.x;
    const int wave = tid >> 6;
    const int lane = tid & 63;
    const int q    = lane >> 4;   // quad 0..3
    const int ln   = lane & 15;
    const int b0   = blockIdx.x * BM;
    const int colb = wave * 32;   // this wave's gate-col base (2 tiles of 16)

    const float INVLN2 = 1.4426950408889634f;

    // ---- Weight B-fragments in registers (bf16, ln2-prescaled). ----
    // B-frag (16x16x32): lane holds col n = lane&15 (+tile base), k = 8*q + j.
    // GEMM1 k: [h(0:128)|x(128:256)] rows of Wu/Wr. GEMM2 k: [x|r*h] rows of Wh.
    bf16x8 wu[2][8], wr[2][8], wh[2][8];
    float nbu[2], nbr[2], bh2[2];
    #pragma unroll
    for (int nt = 0; nt < 2; ++nt) {
        const int c = colb + nt * 16 + ln;
        nbu[nt] = -bu[c] * INVLN2;
        nbr[nt] = -br[c] * INVLN2;
        bh2[nt] = 2.0f * bh[c] * INVLN2;
        #pragma unroll
        for (int kt = 0; kt < 8; ++kt) {
            const int k0 = 32 * kt + 8 * q;
            bf16x8 vu, vr, vh;
            #pragma unroll
            for (int j = 0; j < 8; ++j) {
                vu[j] = (short)f2bf(Wu[(k0 + j) * U_DIM + c] * -INVLN2);
                vr[j] = (short)f2bf(Wr[(k0 + j) * U_DIM + c] * -INVLN2);
                vh[j] = (short)f2bf(Wh[(k0 + j) * U_DIM + c] * (2.0f * INVLN2));
            }
            wu[nt][kt] = vu; wr[nt][kt] = vr; wh[nt][kt] = vh;
        }
    }

    // ---- init ----
    float hreg[2][4];   // fp32 h, row = 4q+r, col = colb+16nt+ln
    #pragma unroll
    for (int nt = 0; nt < 2; ++nt)
        #pragma unroll
        for (int r = 0; r < 4; ++r) hreg[nt][r] = 0.0f;
    for (int i = tid; i < BM * LSTR; i += 256) h_bf[i] = 0;

    // staging map: thread t<192 handles (row = t/CH, step = t%CH) of each chunk
    const int srow  = (tid / CH < BM - 1) ? (tid / CH) : (BM - 1);
    const int sstep = tid % CH;
    const float* srcbase = X   + (size_t)(b0 + srow) * T_LEN * D_DIM;
    const float* abase   = Att + (size_t)(b0 + srow) * T_LEN;

    int t0 = 0;
    for (int c = 0; c < (T_LEN + CH - 1) / CH; ++c) {
        const int L = (t0 + CH <= T_LEN) ? CH : (T_LEN - t0);

        // ---- stage chunk: x -> bf16 LDS in [step][row][col] layout ----
        if (tid < BM * CH && sstep < L) {
            const float* src = srcbase + (size_t)(t0 + sstep) * D_DIM;
            unsigned short* dst = &x_sm[(sstep * BM + srow) * LSTR];
            #pragma unroll
            for (int i = 0; i < 16; ++i) {
                float4 lo = *(const float4*)(src + 8 * i);
                float4 hi = *(const float4*)(src + 8 * i + 4);
                *(bf16x8*)(dst + 8 * i) = pack8(lo, hi);
            }
            a_sm[sstep * BM + srow] = abase[t0 + sstep];
        }
        __syncthreads();

        for (int s = 0; s < L; ++s) {
            // ---------- phase A: frag loads + GEMM1 + GEMM2 x-part ----------
            const unsigned short* hrowp = &h_bf[ln * LSTR + 8 * q];
            const unsigned short* xrowp = &x_sm[(s * BM + ln) * LSTR + 8 * q];
            bf16x8 hfrag[4], xfrag[4];
            #pragma unroll
            for (int kt = 0; kt < 4; ++kt) {
                hfrag[kt] = *(const bf16x8*)(hrowp + 32 * kt);
                xfrag[kt] = *(const bf16x8*)(xrowp + 32 * kt);
            }
            const f32x4 av = *(const f32x4*)&a_sm[s * BM + 4 * q];

            f32x4 accrh[2], accrx[2], accuh[2], accux[2], acch[2];
            #pragma unroll
            for (int nt = 0; nt < 2; ++nt) {
                accrh[nt] = (f32x4)0.0f; accrx[nt] = (f32x4)0.0f;
                accuh[nt] = (f32x4)0.0f; accux[nt] = (f32x4)0.0f;
                acch[nt]  = (f32x4)0.0f;
            }
            // r gate first (needed in phase B)
            #pragma unroll
            for (int kt = 0; kt < 4; ++kt)
                #pragma unroll
                for (int nt = 0; nt < 2; ++nt) {
                    accrh[nt] = __builtin_amdgcn_mfma_f32_16x16x32_bf16(hfrag[kt], wr[nt][kt],     accrh[nt], 0, 0, 0);
                    accrx[nt] = __builtin_amdgcn_mfma_f32_16x16x32_bf16(xfrag[kt], wr[nt][kt + 4], accrx[nt], 0, 0, 0);
                }
            // candidate x-part and u gate (consumed after the barrier)
            #pragma unroll
            for (int kt = 0; kt < 4; ++kt)
                #pragma unroll
                for (int nt = 0; nt < 2; ++nt) {
                    acch[nt]  = __builtin_amdgcn_mfma_f32_16x16x32_bf16(xfrag[kt], wh[nt][kt],     acch[nt],  0, 0, 0);
                    accuh[nt] = __builtin_amdgcn_mfma_f32_16x16x32_bf16(hfrag[kt], wu[nt][kt],     accuh[nt], 0, 0, 0);
                    accux[nt] = __builtin_amdgcn_mfma_f32_16x16x32_bf16(xfrag[kt], wu[nt][kt + 4], accux[nt], 0, 0, 0);
                }

            // ---------- phase B: r gate only; r*h -> LDS (h from fp32 regs) ----------
            #pragma unroll
            for (int nt = 0; nt < 2; ++nt) {
                const int col = colb + nt * 16 + ln;
                #pragma unroll
                for (int r = 0; r < 4; ++r) {
                    float zr = accrh[nt][r] + accrx[nt][r] + nbr[nt];   // = -z_r/ln2
                    float rv = fast_rcp(1.0f + fast_exp2(zr));         // sigmoid
                    rh_bf[(4 * q + r) * LSTR + col] = f2bf(rv * hreg[nt][r]);
                }
            }
            __syncthreads();   // rh handoff

            // ---------- phase C: GEMM2 rh-part; u-gate sigmoid overlaps MFMA ----------
            const unsigned short* rrowp = &rh_bf[ln * LSTR + 8 * q];
            bf16x8 rfrag[4];
            #pragma unroll
            for (int kt = 0; kt < 4; ++kt)
                rfrag[kt] = *(const bf16x8*)(rrowp + 32 * kt);

            float uq[2][4];
            #pragma unroll
            for (int nt = 0; nt < 2; ++nt)
                #pragma unroll
                for (int r = 0; r < 4; ++r) {
                    float zu = accuh[nt][r] + accux[nt][r] + nbu[nt];  // = -z_u/ln2
                    float u  = fast_rcp(1.0f + fast_exp2(zu));         // sigmoid
                    uq[nt][r] = u * av[r];                             // attention-modulated
                }
            #pragma unroll
            for (int kt = 0; kt < 4; ++kt)
                #pragma unroll
                for (int nt = 0; nt < 2; ++nt)
                    acch[nt] = __builtin_amdgcn_mfma_f32_16x16x32_bf16(rfrag[kt], wh[nt][kt + 4], acch[nt], 0, 0, 0);

            // ---------- phase D: tanh, h update (fp32 regs), publish bf16 h ----------
            #pragma unroll
            for (int nt = 0; nt < 2; ++nt) {
                const int col = colb + nt * 16 + ln;
                #pragma unroll
                for (int r = 0; r < 4; ++r) {
                    float z  = acch[nt][r] + bh2[nt];                       // = 2*z_h/ln2
                    float hh = 1.0f - 2.0f * fast_rcp(1.0f + fast_exp2(z)); // tanh
                    float ho = hreg[nt][r];
                    float hn = ho + uq[nt][r] * (hh - ho);                  // u*hh + (1-u)*h
                    hreg[nt][r] = hn;
                    h_bf[(4 * q + r) * LSTR + col] = f2bf(hn);
                }
            }
            __syncthreads();   // h handoff to next step / chunk restage
        }
        t0 += CH;
    }

    // ---- store h_final ----
    #pragma unroll
    for (int nt = 0; nt < 2; ++nt) {
        const int col = colb + nt * 16 + ln;
        #pragma unroll
        for (int r = 0; r < 4; ++r)
            out[(size_t)(b0 + 4 * q + r) * U_DIM + col] = hreg[nt][r];
    }
}

extern "C" void kernel_launch(void* const* d_in, const int* in_sizes, int n_in,
                              void* d_out, int out_size, void* d_ws, size_t ws_size,
                              hipStream_t stream) {
    const float* X   = (const float*)d_in[0];
    const float* Att = (const float*)d_in[1];
    const float* Wu  = (const float*)d_in[2];
    const float* bu  = (const float*)d_in[3];
    const float* Wr  = (const float*)d_in[4];
    const float* br  = (const float*)d_in[5];
    const float* Wh  = (const float*)d_in[6];
    const float* bh  = (const float*)d_in[7];
    float* out = (float*)d_out;

    gru_scan_kernel<<<dim3(2048 / BM), dim3(256), 0, stream>>>(
        X, Att, Wu, bu, Wr, br, Wh, bh, out);
}